// Round 1
// 135.519 us; speedup vs baseline: 1.1696x; 1.1696x over previous
//
#include <hip/hip_runtime.h>
#include <hip/hip_bf16.h>
#include <float.h>

// MoE: n=4096 tokens, D=O=512, E=8, top-2, 3-layer ReLU MLP per expert.
// out[n] = p[n,0]*MLP_{e0}(x[n]) + p[n,1]*MLP_{e1}(x[n])   (slot-indexed probs quirk)
//
// Round-11: atomic-free pipeline.
//  - prep: pack_w (384 blocks) + gate (1024 blocks) fused into one dispatch.
//  - scatter: LDS histogram per block + 8 padded global atomics/block
//    (counters 64B apart at meta[e*16]); also records inv_pos[n][slot].
//  - fused_mlp: stores w-unscaled relu(y) to slot-major f32 y buffer
//    (no atomics, no out pre-zero); depth-2 B prefetch; setprio around MFMA.
//  - combine: out[n] = w0*y[pos0] + w1*y[pos1]  (full overwrite, poison-safe).

#define NTOK   4096
#define DIM    512
#define NEXP   8
#define MATSZ  (DIM * DIM)         // f16 elems per matrix

typedef _Float16 half8 __attribute__((ext_vector_type(8)));
typedef float    f32x4 __attribute__((ext_vector_type(4)));

// ---- workspace layout (bytes) ----
#define META_OFF   0u          // int[256]: counters at [e*16] (64B-padded)
#define TOPE_OFF   1024u       // int[8192]
#define TOPW_OFF   33792u      // float[8192]
#define INV_OFF    66560u      // int[8192]: slot -> entry pos
#define ETOK_OFF   99328u      // int[32768] = 128 KB
#define XH_OFF     230400u     // f16[4096*512] = 4 MB
#define WT_OFF     4424704u    // f16[24*512*512] = 12.6 MB packed
#define Y_OFF      17007616u   // f32[32768*512] = 64 MB slot-major MLP output

// col swizzle: element (row,col) stored at col ^ swz(row); multiples of 8 keep
// half8 runs contiguous and spread C/D row-quads across bank groups.
__device__ __forceinline__ int swz(int row) {
    return ((row & 7) << 3) ^ ((row & 8) << 1);
}

// ---------------- prep: pack weights (blocks 0..383) + gate (blocks 384..1407) ----------------
// pack: W[mat][k][n] f32 -> packed f16: chunk (mat*512 + kc*32 + c16) holds
// B[16 cols][32 k] as one 1KB wave fragment: lane l -> col = c16*16 + (l&15),
// k = kc*32 + (l>>4)*8 + j.
__global__ __launch_bounds__(256)
void prep_kernel(const float* __restrict__ x, const float* __restrict__ gw,
                 const float* __restrict__ gb,
                 const float* __restrict__ W1, const float* __restrict__ W2,
                 const float* __restrict__ W3,
                 int* __restrict__ top_e, float* __restrict__ top_w,
                 _Float16* __restrict__ xh, _Float16* __restrict__ Wt)
{
    __shared__ float s[32 * 513];  // 32 k-rows x 512 cols, +1 pad (pack branch only)
    int bid = blockIdx.x;
    int tid = threadIdx.x;

    if (bid < 384) {
        // ---------------- pack_w ----------------
        int mat = bid >> 4, kc = bid & 15;
        const float* src = ((mat < 8) ? W1 + (size_t)mat * MATSZ
                          : (mat < 16) ? W2 + (size_t)(mat - 8) * MATSZ
                                       : W3 + (size_t)(mat - 16) * MATSZ)
                         + (size_t)kc * 32 * DIM;
#pragma unroll
        for (int i = 0; i < 16; i++) {
            int idx = i * 1024 + tid * 4;
            int k = idx >> 9, c = idx & 511;
            float4 v = *(const float4*)(src + idx);
            float* d = &s[k * 513 + c];
            d[0] = v.x; d[1] = v.y; d[2] = v.z; d[3] = v.w;
        }
        __syncthreads();
        int w = tid >> 6, lane = tid & 63, l15 = lane & 15, l4 = lane >> 4;
#pragma unroll
        for (int i = 0; i < 8; i++) {
            int c16 = w * 8 + i;
            int col = c16 * 16 + l15;
            half8 h;
#pragma unroll
            for (int j = 0; j < 8; j++)
                h[j] = (_Float16)s[(l4 * 8 + j) * 513 + col];
            *(half8*)(Wt + (size_t)mat * MATSZ + (size_t)(kc * 32 + c16) * 512 + lane * 8) = h;
        }
        return;
    }

    // ---------------- gate + x conversion (no out-zero needed anymore) ----------------
    int n = (bid - 384) * 4 + (tid >> 6);
    int lane = tid & 63;

    const float* xr = x + (size_t)n * DIM + lane * 8;
    float4 v0 = *(const float4*)xr;
    float4 v1 = *(const float4*)(xr + 4);
    float xv[8] = {v0.x, v0.y, v0.z, v0.w, v1.x, v1.y, v1.z, v1.w};

    half8 h = { (_Float16)xv[0], (_Float16)xv[1], (_Float16)xv[2], (_Float16)xv[3],
                (_Float16)xv[4], (_Float16)xv[5], (_Float16)xv[6], (_Float16)xv[7] };
    *(half8*)(xh + (size_t)n * DIM + lane * 8) = h;

    float p[NEXP];
#pragma unroll
    for (int e = 0; e < NEXP; e++) p[e] = 0.f;
    const float* g = gw + (size_t)lane * 64;   // rows k = lane*8 .. lane*8+7
#pragma unroll
    for (int j = 0; j < 8; j++)
#pragma unroll
        for (int e = 0; e < NEXP; e++) p[e] += xv[j] * g[j * 8 + e];
#pragma unroll
    for (int e = 0; e < NEXP; e++) {
        float v = p[e];
        for (int off = 32; off; off >>= 1) v += __shfl_xor(v, off, 64);
        p[e] = v;
    }
    if (lane == 0) {
        float l[NEXP];
#pragma unroll
        for (int e = 0; e < NEXP; e++) l[e] = p[e] + gb[e];
        float m = l[0];
#pragma unroll
        for (int e = 1; e < NEXP; e++) m = fmaxf(m, l[e]);
        float ex[NEXP], sum = 0.f;
#pragma unroll
        for (int e = 0; e < NEXP; e++) { ex[e] = expf(l[e] - m); sum += ex[e]; }
        int e0 = 0; float m0 = l[0];
#pragma unroll
        for (int e = 1; e < NEXP; e++) if (l[e] > m0) { m0 = l[e]; e0 = e; }
        int e1 = -1; float m1 = -FLT_MAX;
#pragma unroll
        for (int e = 0; e < NEXP; e++) if (e != e0 && l[e] > m1) { m1 = l[e]; e1 = e; }
        float inv = 1.f / sum;
        int2 te = {e0, e1};
        *(int2*)(top_e + 2 * n) = te;
        float2 tw = {ex[0] * inv, ex[1] * inv};   // slot-indexed probs (reference quirk)
        *(float2*)(top_w + 2 * n) = tw;
    }
}

// ---------------- scatter: LDS histogram + padded global counters ----------------
__global__ __launch_bounds__(256)
void scatter_kernel(const int* __restrict__ top_e, int* __restrict__ meta,
                    int* __restrict__ entry_tok, int* __restrict__ inv_pos)
{
    __shared__ int lcnt[NEXP];
    __shared__ int lbase[NEXP];
    int tid = threadIdx.x;
    if (tid < NEXP) lcnt[tid] = 0;
    __syncthreads();

    int n = blockIdx.x * 256 + tid;
    int2 ee = *(const int2*)(top_e + 2 * n);
    int r0 = atomicAdd(&lcnt[ee.x], 1);       // LDS atomic: intra-block rank
    int r1 = atomicAdd(&lcnt[ee.y], 1);
    __syncthreads();

    if (tid < NEXP) lbase[tid] = atomicAdd(&meta[tid * 16], lcnt[tid]);  // 64B-padded
    __syncthreads();

    int p0 = (ee.x << 12) + lbase[ee.x] + r0;  // fixed 4096-entry region per expert
    int p1 = (ee.y << 12) + lbase[ee.y] + r1;
    entry_tok[p0] = n;
    entry_tok[p1] = n;
    int2 pp = {p0, p1};
    *(int2*)(inv_pos + 2 * n) = pp;
}

// ---------------- fused 3-layer expert MLP: 512 thr, one block per tile ----------------
__global__ __launch_bounds__(512, 2)
void fused_mlp(const _Float16* __restrict__ xh, const _Float16* __restrict__ wt,
               const float* __restrict__ b1, const float* __restrict__ b2,
               const float* __restrict__ b3, float* __restrict__ y,
               const int* __restrict__ meta, const int* __restrict__ entry_tok)
{
    __shared__ _Float16 hbuf[64 * DIM];   // 64 KB, swizzled cols
    __shared__ int rtok[64];

    int bid = blockIdx.x;                 // grid = 8 * 64
    int e = bid & 7;                      // XCD affinity: blockIdx % 8 -> XCD
    int j = bid >> 3;
    int cnt = meta[e * 16];
    if (j >= ((cnt + 63) >> 6)) return;
    int row0 = (e << 12) + (j << 6);      // fixed 4096-row region per expert

    int tid = threadIdx.x;
    int w = tid >> 6, l = tid & 63;
    int l15 = l & 15, l4 = l >> 4;
    int colb = w * 64 + l15;              // wave w owns cols [w*64, w*64+64)

    if (tid < 64)
        rtok[tid] = entry_tok[row0 + tid];   // unwritten slots: 0xAA poison (<0)
    __syncthreads();

    // fill hbuf with gathered x rows: 8 threads/row, 64 cols each
    {
        int row = tid >> 3;
        int c0 = (tid & 7) * 64;
        int tk = rtok[row]; if (tk < 0) tk = 0;   // garbage ok, never read back
        const _Float16* src = xh + (size_t)tk * DIM + c0;
        int f = swz(row);
        _Float16* dst = hbuf + row * DIM;
#pragma unroll
        for (int q = 0; q < 8; q++) {
            half8 v = *(const half8*)(src + q * 8);
            *(half8*)(dst + ((c0 + q * 8) ^ f)) = v;
        }
    }
    __syncthreads();

    f32x4 acc[4][4];

    // one layer: A from hbuf, B reg-streamed with depth-2 prefetch (ring of 3);
    // all indices compile-time (full unroll) so b[] stays in VGPRs.
    auto run_layer = [&](const _Float16* __restrict__ Wp) {
#pragma unroll
        for (int rg = 0; rg < 4; rg++)
#pragma unroll
            for (int cg = 0; cg < 4; cg++) acc[rg][cg] = (f32x4){0.f, 0.f, 0.f, 0.f};
        // wave w uses chunks (kc*32 + w*4 + cg), each 512 f16 (1KB, lane*16B)
        const _Float16* wb = Wp + (size_t)(w * 4) * 512 + (size_t)l * 8;
        half8 b[3][4];
#pragma unroll
        for (int cg = 0; cg < 4; cg++) {
            b[0][cg] = *(const half8*)(wb + (size_t)(0 * 32 + cg) * 512);
            b[1][cg] = *(const half8*)(wb + (size_t)(1 * 32 + cg) * 512);
        }
#pragma unroll
        for (int kc = 0; kc < 16; kc++) {
            const int cur = kc % 3;
            const int pf  = (kc + 2) % 3;
            const int kn  = (kc + 2) & 15;         // wraps on last 2 iters (harmless)
#pragma unroll
            for (int cg = 0; cg < 4; cg++)
                b[pf][cg] = *(const half8*)(wb + (size_t)(kn * 32 + cg) * 512);
            int koff = kc * 32 + l4 * 8;
            half8 af[4];
#pragma unroll
            for (int rg = 0; rg < 4; rg++) {
                int row = rg * 16 + l15;
                af[rg] = *(const half8*)(hbuf + row * DIM + (koff ^ swz(row)));
            }
            __builtin_amdgcn_s_setprio(1);
#pragma unroll
            for (int rg = 0; rg < 4; rg++)
#pragma unroll
                for (int cg = 0; cg < 4; cg++)
                    acc[rg][cg] = __builtin_amdgcn_mfma_f32_16x16x32_f16(af[rg], b[cur][cg], acc[rg][cg], 0, 0, 0);
            __builtin_amdgcn_s_setprio(0);
        }
    };

    // relu(acc + bias) -> hbuf; C/D layout: col=l&15(+16cg), row=l4*4+r(+16rg)
    auto writeback = [&](const float* __restrict__ Bias) {
        float bs[4];
#pragma unroll
        for (int cg = 0; cg < 4; cg++) bs[cg] = Bias[e * DIM + colb + cg * 16];
        __syncthreads();                   // all waves' hbuf reads done
#pragma unroll
        for (int rg = 0; rg < 4; rg++)
#pragma unroll
            for (int r = 0; r < 4; r++) {
                int row = rg * 16 + l4 * 4 + r;
                int f = swz(row);
                _Float16* dst = hbuf + row * DIM;
#pragma unroll
                for (int cg = 0; cg < 4; cg++)
                    dst[(colb + cg * 16) ^ f] = (_Float16)fmaxf(acc[rg][cg][r] + bs[cg], 0.f);
            }
        __syncthreads();                   // next layer may read
    };

    run_layer(wt + (size_t)e * MATSZ);        writeback(b1);
    run_layer(wt + (size_t)(8 + e) * MATSZ);  writeback(b2);
    run_layer(wt + (size_t)(16 + e) * MATSZ);

    // layer-3 epilogue: y[row0+row] = relu(acc + b3)  (plain stores, no atomics;
    // combine_kernel applies the gate weight and sums the two slots per token)
    float bs[4];
#pragma unroll
    for (int cg = 0; cg < 4; cg++) bs[cg] = b3[e * DIM + colb + cg * 16];
    float* yb = y + (size_t)row0 * DIM;
#pragma unroll
    for (int rg = 0; rg < 4; rg++)
#pragma unroll
        for (int r = 0; r < 4; r++) {
            int row = rg * 16 + l4 * 4 + r;
            float* yp = yb + (size_t)row * DIM + colb;
#pragma unroll
            for (int cg = 0; cg < 4; cg++)
                yp[cg * 16] = fmaxf(acc[rg][cg][r] + bs[cg], 0.f);
        }
}

// ---------------- combine: out[n] = w0*y[pos0] + w1*y[pos1] ----------------
__global__ __launch_bounds__(256)
void combine_kernel(const float* __restrict__ y, const int* __restrict__ inv_pos,
                    const float* __restrict__ top_w, float* __restrict__ out)
{
    int tid = threadIdx.x;
    int n = blockIdx.x * 4 + (tid >> 6);
    int lane = tid & 63;
    int2 pp = *(const int2*)(inv_pos + 2 * n);
    float2 tw = *(const float2*)(top_w + 2 * n);
    const float* y0 = y + (size_t)pp.x * DIM + lane * 8;
    const float* y1 = y + (size_t)pp.y * DIM + lane * 8;
    float4 a0 = *(const float4*)y0;
    float4 a1 = *(const float4*)(y0 + 4);
    float4 c0 = *(const float4*)y1;
    float4 c1 = *(const float4*)(y1 + 4);
    float4 o0, o1;
    o0.x = tw.x * a0.x + tw.y * c0.x;
    o0.y = tw.x * a0.y + tw.y * c0.y;
    o0.z = tw.x * a0.z + tw.y * c0.z;
    o0.w = tw.x * a0.w + tw.y * c0.w;
    o1.x = tw.x * a1.x + tw.y * c1.x;
    o1.y = tw.x * a1.y + tw.y * c1.y;
    o1.z = tw.x * a1.z + tw.y * c1.z;
    o1.w = tw.x * a1.w + tw.y * c1.w;
    float* op = out + (size_t)n * DIM + lane * 8;
    *(float4*)op = o0;
    *(float4*)(op + 4) = o1;
}

extern "C" void kernel_launch(void* const* d_in, const int* in_sizes, int n_in,
                              void* d_out, int out_size, void* d_ws, size_t ws_size,
                              hipStream_t stream)
{
    const float* x      = (const float*)d_in[0];
    const float* gate_w = (const float*)d_in[1];
    const float* gate_b = (const float*)d_in[2];
    const float* w1     = (const float*)d_in[3];
    const float* b1     = (const float*)d_in[4];
    const float* w2     = (const float*)d_in[5];
    const float* b2     = (const float*)d_in[6];
    const float* w3     = (const float*)d_in[7];
    const float* b3     = (const float*)d_in[8];
    float* out = (float*)d_out;

    char* ws = (char*)d_ws;
    int*      meta      = (int*)(ws + META_OFF);
    int*      top_e     = (int*)(ws + TOPE_OFF);
    float*    top_w     = (float*)(ws + TOPW_OFF);
    int*      inv_pos   = (int*)(ws + INV_OFF);
    int*      entry_tok = (int*)(ws + ETOK_OFF);
    _Float16* xh        = (_Float16*)(ws + XH_OFF);
    _Float16* wt        = (_Float16*)(ws + WT_OFF);
    float*    yslot     = (float*)(ws + Y_OFF);

    hipMemsetAsync(meta, 0, 1024, stream);

    prep_kernel<<<384 + NTOK / 4, 256, 0, stream>>>(x, gate_w, gate_b, w1, w2, w3,
                                                    top_e, top_w, xh, wt);
    scatter_kernel<<<NTOK / 256, 256, 0, stream>>>(top_e, meta, entry_tok, inv_pos);
    fused_mlp<<<NEXP * 64, 512, 0, stream>>>(xh, wt, b1, b2, b3, yslot,
                                             meta, entry_tok);
    combine_kernel<<<NTOK / 4, 256, 0, stream>>>(yslot, inv_pos, top_w, out);
}

// Round 2
// 131.498 us; speedup vs baseline: 1.2054x; 1.0306x over previous
//
#include <hip/hip_runtime.h>
#include <hip/hip_bf16.h>
#include <float.h>

// MoE: n=4096 tokens, D=O=512, E=8, top-2, 3-layer ReLU MLP per expert.
// out[n] = p[n,0]*MLP_{e0}(x[n]) + p[n,1]*MLP_{e1}(x[n])   (slot-indexed probs quirk)
//
// Round-12: fused_mlp occupancy push.
//  - fused_mlp: 1024 threads (16 waves), same 64x512 block tile (keeps B-stream
//    at the per-XCD optimum), wave covers 64x32 (acc[4][2], B-ring [2][2]).
//    4 waves/SIMD on the live CUs (was 2), VGPR ~90 << 128 cap.
//    Per-layer bias prefetched into regs before the K-loop (kills 3 serial
//    global-load stalls between layers).
//  - prep / scatter / combine unchanged from round-11.

#define NTOK   4096
#define DIM    512
#define NEXP   8
#define MATSZ  (DIM * DIM)         // f16 elems per matrix

typedef _Float16 half8 __attribute__((ext_vector_type(8)));
typedef float    f32x4 __attribute__((ext_vector_type(4)));

// ---- workspace layout (bytes) ----
#define META_OFF   0u          // int[256]: counters at [e*16] (64B-padded)
#define TOPE_OFF   1024u       // int[8192]
#define TOPW_OFF   33792u      // float[8192]
#define INV_OFF    66560u      // int[8192]: slot -> entry pos
#define ETOK_OFF   99328u      // int[32768] = 128 KB
#define XH_OFF     230400u     // f16[4096*512] = 4 MB
#define WT_OFF     4424704u    // f16[24*512*512] = 12.6 MB packed
#define Y_OFF      17007616u   // f32[32768*512] = 64 MB slot-major MLP output

// col swizzle: element (row,col) stored at col ^ swz(row); multiples of 8 keep
// half8 runs contiguous and spread C/D row-quads across bank groups.
__device__ __forceinline__ int swz(int row) {
    return ((row & 7) << 3) ^ ((row & 8) << 1);
}

// ---------------- prep: pack weights (blocks 0..383) + gate (blocks 384..1407) ----------------
// pack: W[mat][k][n] f32 -> packed f16: chunk (mat*512 + kc*32 + c16) holds
// B[16 cols][32 k] as one 1KB wave fragment: lane l -> col = c16*16 + (l&15),
// k = kc*32 + (l>>4)*8 + j.
__global__ __launch_bounds__(256)
void prep_kernel(const float* __restrict__ x, const float* __restrict__ gw,
                 const float* __restrict__ gb,
                 const float* __restrict__ W1, const float* __restrict__ W2,
                 const float* __restrict__ W3,
                 int* __restrict__ top_e, float* __restrict__ top_w,
                 _Float16* __restrict__ xh, _Float16* __restrict__ Wt)
{
    __shared__ float s[32 * 513];  // 32 k-rows x 512 cols, +1 pad (pack branch only)
    int bid = blockIdx.x;
    int tid = threadIdx.x;

    if (bid < 384) {
        // ---------------- pack_w ----------------
        int mat = bid >> 4, kc = bid & 15;
        const float* src = ((mat < 8) ? W1 + (size_t)mat * MATSZ
                          : (mat < 16) ? W2 + (size_t)(mat - 8) * MATSZ
                                       : W3 + (size_t)(mat - 16) * MATSZ)
                         + (size_t)kc * 32 * DIM;
#pragma unroll
        for (int i = 0; i < 16; i++) {
            int idx = i * 1024 + tid * 4;
            int k = idx >> 9, c = idx & 511;
            float4 v = *(const float4*)(src + idx);
            float* d = &s[k * 513 + c];
            d[0] = v.x; d[1] = v.y; d[2] = v.z; d[3] = v.w;
        }
        __syncthreads();
        int w = tid >> 6, lane = tid & 63, l15 = lane & 15, l4 = lane >> 4;
#pragma unroll
        for (int i = 0; i < 8; i++) {
            int c16 = w * 8 + i;
            int col = c16 * 16 + l15;
            half8 h;
#pragma unroll
            for (int j = 0; j < 8; j++)
                h[j] = (_Float16)s[(l4 * 8 + j) * 513 + col];
            *(half8*)(Wt + (size_t)mat * MATSZ + (size_t)(kc * 32 + c16) * 512 + lane * 8) = h;
        }
        return;
    }

    // ---------------- gate + x conversion ----------------
    int n = (bid - 384) * 4 + (tid >> 6);
    int lane = tid & 63;

    const float* xr = x + (size_t)n * DIM + lane * 8;
    float4 v0 = *(const float4*)xr;
    float4 v1 = *(const float4*)(xr + 4);
    float xv[8] = {v0.x, v0.y, v0.z, v0.w, v1.x, v1.y, v1.z, v1.w};

    half8 h = { (_Float16)xv[0], (_Float16)xv[1], (_Float16)xv[2], (_Float16)xv[3],
                (_Float16)xv[4], (_Float16)xv[5], (_Float16)xv[6], (_Float16)xv[7] };
    *(half8*)(xh + (size_t)n * DIM + lane * 8) = h;

    float p[NEXP];
#pragma unroll
    for (int e = 0; e < NEXP; e++) p[e] = 0.f;
    const float* g = gw + (size_t)lane * 64;   // rows k = lane*8 .. lane*8+7
#pragma unroll
    for (int j = 0; j < 8; j++)
#pragma unroll
        for (int e = 0; e < NEXP; e++) p[e] += xv[j] * g[j * 8 + e];
#pragma unroll
    for (int e = 0; e < NEXP; e++) {
        float v = p[e];
        for (int off = 32; off; off >>= 1) v += __shfl_xor(v, off, 64);
        p[e] = v;
    }
    if (lane == 0) {
        float l[NEXP];
#pragma unroll
        for (int e = 0; e < NEXP; e++) l[e] = p[e] + gb[e];
        float m = l[0];
#pragma unroll
        for (int e = 1; e < NEXP; e++) m = fmaxf(m, l[e]);
        float ex[NEXP], sum = 0.f;
#pragma unroll
        for (int e = 0; e < NEXP; e++) { ex[e] = expf(l[e] - m); sum += ex[e]; }
        int e0 = 0; float m0 = l[0];
#pragma unroll
        for (int e = 1; e < NEXP; e++) if (l[e] > m0) { m0 = l[e]; e0 = e; }
        int e1 = -1; float m1 = -FLT_MAX;
#pragma unroll
        for (int e = 0; e < NEXP; e++) if (e != e0 && l[e] > m1) { m1 = l[e]; e1 = e; }
        float inv = 1.f / sum;
        int2 te = {e0, e1};
        *(int2*)(top_e + 2 * n) = te;
        float2 tw = {ex[0] * inv, ex[1] * inv};   // slot-indexed probs (reference quirk)
        *(float2*)(top_w + 2 * n) = tw;
    }
}

// ---------------- scatter: LDS histogram + padded global counters ----------------
__global__ __launch_bounds__(256)
void scatter_kernel(const int* __restrict__ top_e, int* __restrict__ meta,
                    int* __restrict__ entry_tok, int* __restrict__ inv_pos)
{
    __shared__ int lcnt[NEXP];
    __shared__ int lbase[NEXP];
    int tid = threadIdx.x;
    if (tid < NEXP) lcnt[tid] = 0;
    __syncthreads();

    int n = blockIdx.x * 256 + tid;
    int2 ee = *(const int2*)(top_e + 2 * n);
    int r0 = atomicAdd(&lcnt[ee.x], 1);       // LDS atomic: intra-block rank
    int r1 = atomicAdd(&lcnt[ee.y], 1);
    __syncthreads();

    if (tid < NEXP) lbase[tid] = atomicAdd(&meta[tid * 16], lcnt[tid]);  // 64B-padded
    __syncthreads();

    int p0 = (ee.x << 12) + lbase[ee.x] + r0;  // fixed 4096-entry region per expert
    int p1 = (ee.y << 12) + lbase[ee.y] + r1;
    entry_tok[p0] = n;
    entry_tok[p1] = n;
    int2 pp = {p0, p1};
    *(int2*)(inv_pos + 2 * n) = pp;
}

// ---------------- fused 3-layer expert MLP: 1024 thr (16 waves), 64x512 tile ----------------
__global__ __launch_bounds__(1024, 4)
void fused_mlp(const _Float16* __restrict__ xh, const _Float16* __restrict__ wt,
               const float* __restrict__ b1, const float* __restrict__ b2,
               const float* __restrict__ b3, float* __restrict__ y,
               const int* __restrict__ meta, const int* __restrict__ entry_tok)
{
    __shared__ _Float16 hbuf[64 * DIM];   // 64 KB, swizzled cols
    __shared__ int rtok[64];

    int bid = blockIdx.x;                 // grid = 8 * 64
    int e = bid & 7;                      // XCD affinity: blockIdx % 8 -> XCD
    int j = bid >> 3;
    int cnt = meta[e * 16];
    if (j >= ((cnt + 63) >> 6)) return;
    int row0 = (e << 12) + (j << 6);      // fixed 4096-row region per expert

    int tid = threadIdx.x;
    int w = tid >> 6, l = tid & 63;       // w = 0..15
    int l15 = l & 15, l4 = l >> 4;
    int colb = w * 32 + l15;              // wave w owns cols [w*32, w*32+32)

    if (tid < 64)
        rtok[tid] = entry_tok[row0 + tid];   // unwritten slots: 0xAA poison (<0)
    __syncthreads();

    // fill hbuf with gathered x rows: 16 threads/row, 32 cols each
    {
        int row = tid >> 4;
        int c0 = (tid & 15) * 32;
        int tk = rtok[row]; if (tk < 0) tk = 0;   // garbage ok, never read back
        const _Float16* src = xh + (size_t)tk * DIM + c0;
        int f = swz(row);
        _Float16* dst = hbuf + row * DIM;
#pragma unroll
        for (int q = 0; q < 4; q++) {
            half8 v = *(const half8*)(src + q * 8);
            *(half8*)(dst + ((c0 + q * 8) ^ f)) = v;
        }
    }
    __syncthreads();

    f32x4 acc[4][2];
    float bsn[2];
    auto load_bias = [&](const float* __restrict__ B) {
#pragma unroll
        for (int cg = 0; cg < 2; cg++) bsn[cg] = B[e * DIM + colb + cg * 16];
    };

    // one layer: A from hbuf, B reg-streamed with distance-1 double buffer;
    // all indices compile-time (full unroll) so b[] stays in VGPRs.
    auto run_layer = [&](const _Float16* __restrict__ Wp) {
#pragma unroll
        for (int rg = 0; rg < 4; rg++)
#pragma unroll
            for (int cg = 0; cg < 2; cg++) acc[rg][cg] = (f32x4){0.f, 0.f, 0.f, 0.f};
        // wave w uses chunks (kc*32 + w*2 + cg), each 512 f16 (1KB, lane*16B)
        const _Float16* wb = Wp + (size_t)(w * 2) * 512 + (size_t)l * 8;
        half8 b[2][2];
#pragma unroll
        for (int cg = 0; cg < 2; cg++)
            b[0][cg] = *(const half8*)(wb + (size_t)cg * 512);
#pragma unroll
        for (int kc = 0; kc < 16; kc++) {
            const int cur = kc & 1, nxt = cur ^ 1;
            const int kn = (kc + 1) & 15;          // wraps on last iter (harmless)
#pragma unroll
            for (int cg = 0; cg < 2; cg++)
                b[nxt][cg] = *(const half8*)(wb + (size_t)(kn * 32 + cg) * 512);
            int koff = kc * 32 + l4 * 8;
            half8 af[4];
#pragma unroll
            for (int rg = 0; rg < 4; rg++) {
                int row = rg * 16 + l15;
                af[rg] = *(const half8*)(hbuf + row * DIM + (koff ^ swz(row)));
            }
            __builtin_amdgcn_s_setprio(1);
#pragma unroll
            for (int rg = 0; rg < 4; rg++)
#pragma unroll
                for (int cg = 0; cg < 2; cg++)
                    acc[rg][cg] = __builtin_amdgcn_mfma_f32_16x16x32_f16(af[rg], b[cur][cg], acc[rg][cg], 0, 0, 0);
            __builtin_amdgcn_s_setprio(0);
        }
    };

    // relu(acc + bias) -> hbuf; C/D layout: col=l&15(+16cg), row=l4*4+r(+16rg)
    auto writeback = [&]() {
        __syncthreads();                   // all waves' hbuf reads done
#pragma unroll
        for (int rg = 0; rg < 4; rg++)
#pragma unroll
            for (int r = 0; r < 4; r++) {
                int row = rg * 16 + l4 * 4 + r;
                int f = swz(row);
                _Float16* dst = hbuf + row * DIM;
#pragma unroll
                for (int cg = 0; cg < 2; cg++)
                    dst[(colb + cg * 16) ^ f] = (_Float16)fmaxf(acc[rg][cg][r] + bsn[cg], 0.f);
            }
        __syncthreads();                   // next layer may read
    };

    load_bias(b1);
    run_layer(wt + (size_t)e * MATSZ);        writeback();
    load_bias(b2);
    run_layer(wt + (size_t)(8 + e) * MATSZ);  writeback();
    load_bias(b3);
    run_layer(wt + (size_t)(16 + e) * MATSZ);

    // layer-3 epilogue: y[row0+row] = relu(acc + b3)  (plain stores, no atomics;
    // combine_kernel applies the gate weight and sums the two slots per token)
    float* yb = y + (size_t)row0 * DIM;
#pragma unroll
    for (int rg = 0; rg < 4; rg++)
#pragma unroll
        for (int r = 0; r < 4; r++) {
            int row = rg * 16 + l4 * 4 + r;
            float* yp = yb + (size_t)row * DIM + colb;
#pragma unroll
            for (int cg = 0; cg < 2; cg++)
                yp[cg * 16] = fmaxf(acc[rg][cg][r] + bsn[cg], 0.f);
        }
}

// ---------------- combine: out[n] = w0*y[pos0] + w1*y[pos1] ----------------
__global__ __launch_bounds__(256)
void combine_kernel(const float* __restrict__ y, const int* __restrict__ inv_pos,
                    const float* __restrict__ top_w, float* __restrict__ out)
{
    int tid = threadIdx.x;
    int n = blockIdx.x * 4 + (tid >> 6);
    int lane = tid & 63;
    int2 pp = *(const int2*)(inv_pos + 2 * n);
    float2 tw = *(const float2*)(top_w + 2 * n);
    const float* y0 = y + (size_t)pp.x * DIM + lane * 8;
    const float* y1 = y + (size_t)pp.y * DIM + lane * 8;
    float4 a0 = *(const float4*)y0;
    float4 a1 = *(const float4*)(y0 + 4);
    float4 c0 = *(const float4*)y1;
    float4 c1 = *(const float4*)(y1 + 4);
    float4 o0, o1;
    o0.x = tw.x * a0.x + tw.y * c0.x;
    o0.y = tw.x * a0.y + tw.y * c0.y;
    o0.z = tw.x * a0.z + tw.y * c0.z;
    o0.w = tw.x * a0.w + tw.y * c0.w;
    o1.x = tw.x * a1.x + tw.y * c1.x;
    o1.y = tw.x * a1.y + tw.y * c1.y;
    o1.z = tw.x * a1.z + tw.y * c1.z;
    o1.w = tw.x * a1.w + tw.y * c1.w;
    float* op = out + (size_t)n * DIM + lane * 8;
    *(float4*)op = o0;
    *(float4*)(op + 4) = o1;
}

extern "C" void kernel_launch(void* const* d_in, const int* in_sizes, int n_in,
                              void* d_out, int out_size, void* d_ws, size_t ws_size,
                              hipStream_t stream)
{
    const float* x      = (const float*)d_in[0];
    const float* gate_w = (const float*)d_in[1];
    const float* gate_b = (const float*)d_in[2];
    const float* w1     = (const float*)d_in[3];
    const float* b1     = (const float*)d_in[4];
    const float* w2     = (const float*)d_in[5];
    const float* b2     = (const float*)d_in[6];
    const float* w3     = (const float*)d_in[7];
    const float* b3     = (const float*)d_in[8];
    float* out = (float*)d_out;

    char* ws = (char*)d_ws;
    int*      meta      = (int*)(ws + META_OFF);
    int*      top_e     = (int*)(ws + TOPE_OFF);
    float*    top_w     = (float*)(ws + TOPW_OFF);
    int*      inv_pos   = (int*)(ws + INV_OFF);
    int*      entry_tok = (int*)(ws + ETOK_OFF);
    _Float16* xh        = (_Float16*)(ws + XH_OFF);
    _Float16* wt        = (_Float16*)(ws + WT_OFF);
    float*    yslot     = (float*)(ws + Y_OFF);

    hipMemsetAsync(meta, 0, 1024, stream);

    prep_kernel<<<384 + NTOK / 4, 256, 0, stream>>>(x, gate_w, gate_b, w1, w2, w3,
                                                    top_e, top_w, xh, wt);
    scatter_kernel<<<NTOK / 256, 256, 0, stream>>>(top_e, meta, entry_tok, inv_pos);
    fused_mlp<<<NEXP * 64, 1024, 0, stream>>>(xh, wt, b1, b2, b3, yslot,
                                              meta, entry_tok);
    combine_kernel<<<NTOK / 4, 256, 0, stream>>>(yslot, inv_pos, top_w, out);
}